// Round 1
// baseline (306.543 us; speedup 1.0000x reference)
//
#include <hip/hip_runtime.h>
#include <math.h>

#define NL 6
#define DD 128
#define HH 16

__device__ __forceinline__ float fast_tanh(float v){
    float xc = fminf(fmaxf(v, -15.f), 15.f);
    float e2 = exp2f(xc * 2.885390081777927f);   // e^(2x) = 2^(2x/ln2)
    return (e2 - 1.f) * __builtin_amdgcn_rcpf(e2 + 1.f);
}

__device__ __forceinline__ void dense16_relu(float (&h)[16],
                                             const float* __restrict__ W,
                                             const float* __restrict__ b){
    float o[16];
    #pragma unroll
    for (int j = 0; j < 16; ++j){
        float a = b[j];
        #pragma unroll
        for (int i = 0; i < 16; ++i)
            a = fmaf(h[i], W[i*16 + j], a);
        o[j] = fmaxf(a, 0.f);
    }
    #pragma unroll
    for (int j = 0; j < 16; ++j) h[j] = o[j];
}

__global__ __launch_bounds__(64)
void realnvp_fwd(const float* __restrict__ X,
    const float* __restrict__ tW1, const float* __restrict__ tb1,
    const float* __restrict__ tW2, const float* __restrict__ tb2,
    const float* __restrict__ tW3, const float* __restrict__ tb3,
    const float* __restrict__ tW4, const float* __restrict__ tb4,
    const float* __restrict__ tW5, const float* __restrict__ tb5,
    const float* __restrict__ sW1, const float* __restrict__ sb1,
    const float* __restrict__ sW2, const float* __restrict__ sb2,
    const float* __restrict__ sW3, const float* __restrict__ sb3,
    const float* __restrict__ sW4, const float* __restrict__ sb4,
    const float* __restrict__ sW5, const float* __restrict__ sb5,
    float* __restrict__ Y, float* __restrict__ LD, int B)
{
    // per-thread scratch for the "active" 64 coords; pad 65 -> bank (t+i)%32 (2-way, free)
    __shared__ float lds[64 * 65];
    const int tid = threadIdx.x;
    const int row = blockIdx.x * 64 + tid;
    if (row >= B) return;
    const int base = tid * 65;

    // Initial layout: first processed layer is l=5, masks[5][0]=1 -> active=[0,64), passive=[64,128)
    const float4* xr = reinterpret_cast<const float4*>(X + (size_t)row * DD);
    float xp[64];                       // passive half, statically indexed (registers)
    #pragma unroll
    for (int i = 0; i < 16; ++i){
        float4 v = xr[i];
        lds[base + 4*i + 0] = v.x; lds[base + 4*i + 1] = v.y;
        lds[base + 4*i + 2] = v.z; lds[base + 4*i + 3] = v.w;
    }
    #pragma unroll
    for (int i = 0; i < 16; ++i){
        float4 v = xr[16 + i];
        xp[4*i + 0] = v.x; xp[4*i + 1] = v.y; xp[4*i + 2] = v.z; xp[4*i + 3] = v.w;
    }

    float ld = 0.f;

    #pragma unroll 1
    for (int step = 0; step < NL; ++step){
        const int l = NL - 1 - step;                 // layers iterated in reverse
        const int aOff = (l & 1) ? 0 : 64;           // masks[l][0]==1 iff l odd
        const int pOff = 64 - aOff;

        const float* __restrict__ w1t = tW1 + l * (DD*HH) + aOff * HH;
        const float* __restrict__ w1s = sW1 + l * (DD*HH) + aOff * HH;
        const float* __restrict__ b1t = tb1 + l * HH;
        const float* __restrict__ b1s = sb1 + l * HH;

        float ht[16], hs[16];
        #pragma unroll
        for (int o = 0; o < 16; ++o){ ht[o] = b1t[o]; hs[o] = b1s[o]; }

        // trunk layer 1: only the 64 active inputs are nonzero
        #pragma unroll 4
        for (int i = 0; i < 64; ++i){
            float xa = lds[base + i];
            #pragma unroll
            for (int o = 0; o < 16; ++o){
                ht[o] = fmaf(xa, w1t[i*HH + o], ht[o]);
                hs[o] = fmaf(xa, w1s[i*HH + o], hs[o]);
            }
        }
        #pragma unroll
        for (int o = 0; o < 16; ++o){ ht[o] = fmaxf(ht[o], 0.f); hs[o] = fmaxf(hs[o], 0.f); }

        dense16_relu(ht, tW2 + l*256, tb2 + l*16);
        dense16_relu(hs, sW2 + l*256, sb2 + l*16);
        dense16_relu(ht, tW3 + l*256, tb3 + l*16);
        dense16_relu(hs, sW3 + l*256, sb3 + l*16);
        dense16_relu(ht, tW4 + l*256, tb4 + l*16);
        dense16_relu(hs, sW4 + l*256, sb4 + l*16);

        // linear heads: only the 64 passive outputs survive rm
        const float* __restrict__ w5t = tW5 + l * (HH*DD) + pOff;
        const float* __restrict__ w5s = sW5 + l * (HH*DD) + pOff;
        const float* __restrict__ b5t = tb5 + l * DD + pOff;
        const float* __restrict__ b5s = sb5 + l * DD + pOff;

        #pragma unroll
        for (int jb = 0; jb < 4; ++jb){
            float tv[16], sv[16];
            #pragma unroll
            for (int jj = 0; jj < 16; ++jj){ tv[jj] = b5t[jb*16 + jj]; sv[jj] = b5s[jb*16 + jj]; }
            #pragma unroll
            for (int k = 0; k < 16; ++k){
                const float a1 = ht[k], a2 = hs[k];
                #pragma unroll
                for (int jj = 0; jj < 16; ++jj){
                    tv[jj] = fmaf(a1, w5t[k*DD + jb*16 + jj], tv[jj]);
                    sv[jj] = fmaf(a2, w5s[k*DD + jb*16 + jj], sv[jj]);
                }
            }
            #pragma unroll
            for (int jj = 0; jj < 16; ++jj){
                float se = fast_tanh(sv[jj]);
                float e  = exp2f(se * -1.4426950408889634f);   // exp(-s)
                xp[jb*16 + jj] = (xp[jb*16 + jj] - tv[jj]) * e;
                ld -= se;
            }
        }

        // swap halves: updated passive (regs) becomes next layer's active (LDS), and vice versa
        #pragma unroll
        for (int i = 0; i < 64; ++i){
            float tmp = lds[base + i];
            lds[base + i] = xp[i];
            xp[i] = tmp;
        }
    }

    // after l=0 (+swap): LDS holds coords [0,64), xp holds coords [64,128)
    float4* yr = reinterpret_cast<float4*>(Y + (size_t)row * DD);
    #pragma unroll
    for (int i = 0; i < 16; ++i){
        float4 v;
        v.x = lds[base + 4*i + 0]; v.y = lds[base + 4*i + 1];
        v.z = lds[base + 4*i + 2]; v.w = lds[base + 4*i + 3];
        yr[i] = v;
    }
    #pragma unroll
    for (int i = 0; i < 16; ++i){
        float4 v;
        v.x = xp[4*i + 0]; v.y = xp[4*i + 1]; v.z = xp[4*i + 2]; v.w = xp[4*i + 3];
        yr[16 + i] = v;
    }
    LD[row] = ld;
}

extern "C" void kernel_launch(void* const* d_in, const int* in_sizes, int n_in,
                              void* d_out, int out_size, void* d_ws, size_t ws_size,
                              hipStream_t stream)
{
    const float* X   = (const float*)d_in[0];
    // d_in[1] = masks: construction is fixed ([0]*64+[1]*64 alternating); parity hardcoded
    const float* tW1 = (const float*)d_in[2];  const float* tb1 = (const float*)d_in[3];
    const float* tW2 = (const float*)d_in[4];  const float* tb2 = (const float*)d_in[5];
    const float* tW3 = (const float*)d_in[6];  const float* tb3 = (const float*)d_in[7];
    const float* tW4 = (const float*)d_in[8];  const float* tb4 = (const float*)d_in[9];
    const float* tW5 = (const float*)d_in[10]; const float* tb5 = (const float*)d_in[11];
    const float* sW1 = (const float*)d_in[12]; const float* sb1 = (const float*)d_in[13];
    const float* sW2 = (const float*)d_in[14]; const float* sb2 = (const float*)d_in[15];
    const float* sW3 = (const float*)d_in[16]; const float* sb3 = (const float*)d_in[17];
    const float* sW4 = (const float*)d_in[18]; const float* sb4 = (const float*)d_in[19];
    const float* sW5 = (const float*)d_in[20]; const float* sb5 = (const float*)d_in[21];

    const int B = in_sizes[0] / DD;
    float* Y  = (float*)d_out;
    float* LD = Y + (size_t)B * DD;

    const int grid = (B + 63) / 64;
    hipLaunchKernelGGL(realnvp_fwd, dim3(grid), dim3(64), 0, stream,
                       X, tW1, tb1, tW2, tb2, tW3, tb3, tW4, tb4, tW5, tb5,
                       sW1, sb1, sW2, sb2, sW3, sb3, sW4, sb4, sW5, sb5,
                       Y, LD, B);
}

// Round 2
// 251.164 us; speedup vs baseline: 1.2205x; 1.2205x over previous
//
#include <hip/hip_runtime.h>
#include <math.h>

#define NL 6
#define DD 128
#define HH 16

typedef float v2f __attribute__((ext_vector_type(2)));

// packed-layer layout in d_ws (v2f units): per layer l:
//   [0,2048)    W1  (128 x 16)   (t,s) interleaved
//   [2048,2304) W2  (16 x 16)
//   [2304,2560) W3
//   [2560,2816) W4
//   [2816,4864) W5  (16 x 128)
//   [4864,4880) b1, [4880,4896) b2, [4896,4912) b3, [4912,4928) b4
//   [4928,5056) b5 (128)
#define L_F2 5056

__device__ __forceinline__ v2f pk_fma(v2f a, v2f b, v2f c){
#if __has_builtin(__builtin_elementwise_fma)
    return __builtin_elementwise_fma(a, b, c);
#else
    v2f r; r.x = fmaf(a.x, b.x, c.x); r.y = fmaf(a.y, b.y, c.y); return r;
#endif
}
__device__ __forceinline__ v2f pk_relu(v2f a){
#if __has_builtin(__builtin_elementwise_max)
    return __builtin_elementwise_max(a, (v2f)0.f);
#else
    v2f r; r.x = fmaxf(a.x, 0.f); r.y = fmaxf(a.y, 0.f); return r;
#endif
}

__global__ void pack_weights(
    const float* __restrict__ tW1, const float* __restrict__ sW1,
    const float* __restrict__ tW2, const float* __restrict__ sW2,
    const float* __restrict__ tW3, const float* __restrict__ sW3,
    const float* __restrict__ tW4, const float* __restrict__ sW4,
    const float* __restrict__ tW5, const float* __restrict__ sW5,
    const float* __restrict__ tb1, const float* __restrict__ sb1,
    const float* __restrict__ tb2, const float* __restrict__ sb2,
    const float* __restrict__ tb3, const float* __restrict__ sb3,
    const float* __restrict__ tb4, const float* __restrict__ sb4,
    const float* __restrict__ tb5, const float* __restrict__ sb5,
    v2f* __restrict__ pw)
{
    const int l = blockIdx.x, t = threadIdx.x;
    v2f* base = pw + (size_t)l * L_F2;
    for (int i = t; i < 2048; i += 256) base[i]        = (v2f){tW1[l*2048+i], sW1[l*2048+i]};
    for (int i = t; i < 256;  i += 256) base[2048+i]   = (v2f){tW2[l*256 +i], sW2[l*256 +i]};
    for (int i = t; i < 256;  i += 256) base[2304+i]   = (v2f){tW3[l*256 +i], sW3[l*256 +i]};
    for (int i = t; i < 256;  i += 256) base[2560+i]   = (v2f){tW4[l*256 +i], sW4[l*256 +i]};
    for (int i = t; i < 2048; i += 256) base[2816+i]   = (v2f){tW5[l*2048+i], sW5[l*2048+i]};
    if (t < 16){
        base[4864+t] = (v2f){tb1[l*16+t], sb1[l*16+t]};
        base[4880+t] = (v2f){tb2[l*16+t], sb2[l*16+t]};
        base[4896+t] = (v2f){tb3[l*16+t], sb3[l*16+t]};
        base[4912+t] = (v2f){tb4[l*16+t], sb4[l*16+t]};
    }
    for (int i = t; i < 128; i += 256) base[4928+i] = (v2f){tb5[l*128+i], sb5[l*128+i]};
}

__global__ __launch_bounds__(64)
void realnvp_fwd_pk(const float* __restrict__ X, const v2f* __restrict__ PW,
                    float* __restrict__ Y, float* __restrict__ LD, int B)
{
    // active half: 64 floats/thread in LDS, stride 68 (272B = 17*16B -> odd float4 stride, conflict-free b128)
    __shared__ float lds[64 * 68];
    const int tid = threadIdx.x;
    const int row = blockIdx.x * 64 + tid;
    if (row >= B) return;
    float4* a4 = reinterpret_cast<float4*>(lds + tid * 68);

    const float4* xr = reinterpret_cast<const float4*>(X + (size_t)row * DD);
    float xp[64];                                     // passive half (static-indexed regs)
    #pragma unroll
    for (int i = 0; i < 16; ++i) a4[i] = xr[i];       // first layer l=5: active = coords [0,64)
    #pragma unroll
    for (int i = 0; i < 16; ++i){
        float4 v = xr[16 + i];
        xp[4*i] = v.x; xp[4*i+1] = v.y; xp[4*i+2] = v.z; xp[4*i+3] = v.w;
    }

    float ldv = 0.f;

    #pragma unroll 1
    for (int step = 0; step < NL; ++step){
        const int l = NL - 1 - step;
        const int aOff = (l & 1) ? 0 : 64;
        const int pOff = 64 - aOff;
        const v2f* __restrict__ LB = PW + (size_t)l * L_F2;

        // ---- trunk layer 1: h = relu(a @ W1[aOff:aOff+64] + b1), both nets packed ----
        v2f h[16];
        {
            const v2f* __restrict__ b1 = LB + 4864;
            #pragma unroll
            for (int o = 0; o < 16; ++o) h[o] = b1[o];
        }
        const v2f* __restrict__ w1 = LB + aOff * 16;
        #pragma unroll 2
        for (int c = 0; c < 16; ++c){
            float4 av = a4[c];
            const v2f* __restrict__ wc = w1 + c * 64;
            v2f s0 = {av.x, av.x}, s1 = {av.y, av.y}, s2 = {av.z, av.z}, s3 = {av.w, av.w};
            #pragma unroll
            for (int o = 0; o < 16; ++o){
                h[o] = pk_fma(s0, wc[o],      h[o]);
                h[o] = pk_fma(s1, wc[16 + o], h[o]);
                h[o] = pk_fma(s2, wc[32 + o], h[o]);
                h[o] = pk_fma(s3, wc[48 + o], h[o]);
            }
        }
        #pragma unroll
        for (int o = 0; o < 16; ++o) h[o] = pk_relu(h[o]);

        // ---- 3 hidden dense16 layers ----
        #pragma unroll 1
        for (int c = 0; c < 3; ++c){
            const v2f* __restrict__ w = LB + 2048 + c * 256;
            const v2f* __restrict__ b = LB + 4880 + c * 16;
            v2f o_[16];
            #pragma unroll
            for (int j = 0; j < 16; ++j) o_[j] = b[j];
            #pragma unroll
            for (int i = 0; i < 16; ++i){
                #pragma unroll
                for (int j = 0; j < 16; ++j) o_[j] = pk_fma(h[i], w[i*16 + j], o_[j]);
            }
            #pragma unroll
            for (int j = 0; j < 16; ++j) h[j] = pk_relu(o_[j]);
        }

        // ---- linear heads (passive 64 outputs) + epilogue + fused half-swap ----
        const v2f* __restrict__ w5 = LB + 2816 + pOff;
        const v2f* __restrict__ b5 = LB + 4928 + pOff;
        #pragma unroll
        for (int jb = 0; jb < 4; ++jb){
            v2f o_[16];
            #pragma unroll
            for (int j = 0; j < 16; ++j) o_[j] = b5[jb*16 + j];
            #pragma unroll
            for (int k = 0; k < 16; ++k){
                #pragma unroll
                for (int j = 0; j < 16; ++j) o_[j] = pk_fma(h[k], w5[k*128 + jb*16 + j], o_[j]);
            }
            float nw[16];
            #pragma unroll
            for (int j = 0; j < 16; ++j){
                float tv = o_[j].x, sv = o_[j].y;
                float xc = fminf(fmaxf(sv, -15.f), 15.f);
                float e2 = exp2f(xc * 2.885390081777927f);        // e^(2x)
                float se = (e2 - 1.f) * __builtin_amdgcn_rcpf(e2 + 1.f);   // tanh
                float e  = exp2f(se * -1.4426950408889634f);      // exp(-s)
                nw[j] = (xp[jb*16 + j] - tv) * e;
                ldv -= se;
            }
            // fused swap: new active (updated passive) -> LDS; old active -> xp regs
            #pragma unroll
            for (int q = 0; q < 4; ++q){
                float4 oldc = a4[jb*4 + q];
                a4[jb*4 + q] = (float4){nw[4*q], nw[4*q+1], nw[4*q+2], nw[4*q+3]};
                xp[jb*16 + 4*q + 0] = oldc.x; xp[jb*16 + 4*q + 1] = oldc.y;
                xp[jb*16 + 4*q + 2] = oldc.z; xp[jb*16 + 4*q + 3] = oldc.w;
            }
        }
    }

    // final layout: LDS = coords [0,64), xp = coords [64,128)
    float4* yr = reinterpret_cast<float4*>(Y + (size_t)row * DD);
    #pragma unroll
    for (int i = 0; i < 16; ++i) yr[i] = a4[i];
    #pragma unroll
    for (int i = 0; i < 16; ++i)
        yr[16 + i] = (float4){xp[4*i], xp[4*i+1], xp[4*i+2], xp[4*i+3]};
    LD[row] = ldv;
}

// ---------------- fallback (no workspace): round-1 kernel, known good ----------------
__device__ __forceinline__ float fast_tanh(float v){
    float xc = fminf(fmaxf(v, -15.f), 15.f);
    float e2 = exp2f(xc * 2.885390081777927f);
    return (e2 - 1.f) * __builtin_amdgcn_rcpf(e2 + 1.f);
}
__device__ __forceinline__ void dense16_relu(float (&h)[16],
                                             const float* __restrict__ W,
                                             const float* __restrict__ b){
    float o[16];
    #pragma unroll
    for (int j = 0; j < 16; ++j){
        float a = b[j];
        #pragma unroll
        for (int i = 0; i < 16; ++i) a = fmaf(h[i], W[i*16 + j], a);
        o[j] = fmaxf(a, 0.f);
    }
    #pragma unroll
    for (int j = 0; j < 16; ++j) h[j] = o[j];
}
__global__ __launch_bounds__(64)
void realnvp_fwd_v1(const float* __restrict__ X,
    const float* __restrict__ tW1, const float* __restrict__ tb1,
    const float* __restrict__ tW2, const float* __restrict__ tb2,
    const float* __restrict__ tW3, const float* __restrict__ tb3,
    const float* __restrict__ tW4, const float* __restrict__ tb4,
    const float* __restrict__ tW5, const float* __restrict__ tb5,
    const float* __restrict__ sW1, const float* __restrict__ sb1,
    const float* __restrict__ sW2, const float* __restrict__ sb2,
    const float* __restrict__ sW3, const float* __restrict__ sb3,
    const float* __restrict__ sW4, const float* __restrict__ sb4,
    const float* __restrict__ sW5, const float* __restrict__ sb5,
    float* __restrict__ Y, float* __restrict__ LD, int B)
{
    __shared__ float lds[64 * 65];
    const int tid = threadIdx.x;
    const int row = blockIdx.x * 64 + tid;
    if (row >= B) return;
    const int base = tid * 65;
    const float4* xr = reinterpret_cast<const float4*>(X + (size_t)row * DD);
    float xp[64];
    #pragma unroll
    for (int i = 0; i < 16; ++i){
        float4 v = xr[i];
        lds[base+4*i] = v.x; lds[base+4*i+1] = v.y; lds[base+4*i+2] = v.z; lds[base+4*i+3] = v.w;
    }
    #pragma unroll
    for (int i = 0; i < 16; ++i){
        float4 v = xr[16+i];
        xp[4*i] = v.x; xp[4*i+1] = v.y; xp[4*i+2] = v.z; xp[4*i+3] = v.w;
    }
    float ld = 0.f;
    #pragma unroll 1
    for (int step = 0; step < NL; ++step){
        const int l = NL - 1 - step;
        const int aOff = (l & 1) ? 0 : 64;
        const int pOff = 64 - aOff;
        const float* w1t = tW1 + l*(DD*HH) + aOff*HH;
        const float* w1s = sW1 + l*(DD*HH) + aOff*HH;
        float ht[16], hs[16];
        #pragma unroll
        for (int o = 0; o < 16; ++o){ ht[o] = tb1[l*HH+o]; hs[o] = sb1[l*HH+o]; }
        #pragma unroll 4
        for (int i = 0; i < 64; ++i){
            float xa = lds[base + i];
            #pragma unroll
            for (int o = 0; o < 16; ++o){
                ht[o] = fmaf(xa, w1t[i*HH+o], ht[o]);
                hs[o] = fmaf(xa, w1s[i*HH+o], hs[o]);
            }
        }
        #pragma unroll
        for (int o = 0; o < 16; ++o){ ht[o] = fmaxf(ht[o],0.f); hs[o] = fmaxf(hs[o],0.f); }
        dense16_relu(ht, tW2 + l*256, tb2 + l*16);
        dense16_relu(hs, sW2 + l*256, sb2 + l*16);
        dense16_relu(ht, tW3 + l*256, tb3 + l*16);
        dense16_relu(hs, sW3 + l*256, sb3 + l*16);
        dense16_relu(ht, tW4 + l*256, tb4 + l*16);
        dense16_relu(hs, sW4 + l*256, sb4 + l*16);
        const float* w5t = tW5 + l*(HH*DD) + pOff;
        const float* w5s = sW5 + l*(HH*DD) + pOff;
        #pragma unroll
        for (int jb = 0; jb < 4; ++jb){
            float tv[16], sv[16];
            #pragma unroll
            for (int jj = 0; jj < 16; ++jj){ tv[jj] = tb5[l*DD+pOff+jb*16+jj]; sv[jj] = sb5[l*DD+pOff+jb*16+jj]; }
            #pragma unroll
            for (int k = 0; k < 16; ++k){
                const float a1 = ht[k], a2 = hs[k];
                #pragma unroll
                for (int jj = 0; jj < 16; ++jj){
                    tv[jj] = fmaf(a1, w5t[k*DD+jb*16+jj], tv[jj]);
                    sv[jj] = fmaf(a2, w5s[k*DD+jb*16+jj], sv[jj]);
                }
            }
            #pragma unroll
            for (int jj = 0; jj < 16; ++jj){
                float se = fast_tanh(sv[jj]);
                float e  = exp2f(se * -1.4426950408889634f);
                xp[jb*16+jj] = (xp[jb*16+jj] - tv[jj]) * e;
                ld -= se;
            }
        }
        #pragma unroll
        for (int i = 0; i < 64; ++i){
            float tmp = lds[base + i]; lds[base + i] = xp[i]; xp[i] = tmp;
        }
    }
    float4* yr = reinterpret_cast<float4*>(Y + (size_t)row * DD);
    #pragma unroll
    for (int i = 0; i < 16; ++i)
        yr[i] = (float4){lds[base+4*i], lds[base+4*i+1], lds[base+4*i+2], lds[base+4*i+3]};
    #pragma unroll
    for (int i = 0; i < 16; ++i)
        yr[16+i] = (float4){xp[4*i], xp[4*i+1], xp[4*i+2], xp[4*i+3]};
    LD[row] = ld;
}

extern "C" void kernel_launch(void* const* d_in, const int* in_sizes, int n_in,
                              void* d_out, int out_size, void* d_ws, size_t ws_size,
                              hipStream_t stream)
{
    const float* X   = (const float*)d_in[0];
    const float* tW1 = (const float*)d_in[2];  const float* tb1 = (const float*)d_in[3];
    const float* tW2 = (const float*)d_in[4];  const float* tb2 = (const float*)d_in[5];
    const float* tW3 = (const float*)d_in[6];  const float* tb3 = (const float*)d_in[7];
    const float* tW4 = (const float*)d_in[8];  const float* tb4 = (const float*)d_in[9];
    const float* tW5 = (const float*)d_in[10]; const float* tb5 = (const float*)d_in[11];
    const float* sW1 = (const float*)d_in[12]; const float* sb1 = (const float*)d_in[13];
    const float* sW2 = (const float*)d_in[14]; const float* sb2 = (const float*)d_in[15];
    const float* sW3 = (const float*)d_in[16]; const float* sb3 = (const float*)d_in[17];
    const float* sW4 = (const float*)d_in[18]; const float* sb4 = (const float*)d_in[19];
    const float* sW5 = (const float*)d_in[20]; const float* sb5 = (const float*)d_in[21];

    const int B = in_sizes[0] / DD;
    float* Y  = (float*)d_out;
    float* LD = Y + (size_t)B * DD;
    const int grid = (B + 63) / 64;

    const size_t need = (size_t)NL * L_F2 * sizeof(v2f);   // 242,688 B
    if (ws_size >= need){
        v2f* pw = (v2f*)d_ws;
        hipLaunchKernelGGL(pack_weights, dim3(NL), dim3(256), 0, stream,
                           tW1, sW1, tW2, sW2, tW3, sW3, tW4, sW4, tW5, sW5,
                           tb1, sb1, tb2, sb2, tb3, sb3, tb4, sb4, tb5, sb5, pw);
        hipLaunchKernelGGL(realnvp_fwd_pk, dim3(grid), dim3(64), 0, stream, X, pw, Y, LD, B);
    } else {
        hipLaunchKernelGGL(realnvp_fwd_v1, dim3(grid), dim3(64), 0, stream,
                           X, tW1, tb1, tW2, tb2, tW3, tb3, tW4, tb4, tW5, tb5,
                           sW1, sb1, sW2, sb2, sW3, sb3, sW4, sb4, sW5, sb5, Y, LD, B);
    }
}